// Round 9
// baseline (798.534 us; speedup 1.0000x reference)
//
#include <hip/hip_runtime.h>
#include <math.h>

#define TWO_PI_F 6.283185307179586f
#define PI_4_F   0.7853981633974483f

typedef __attribute__((ext_vector_type(8))) short short8;
typedef __attribute__((ext_vector_type(4))) float f32x4;
typedef __attribute__((ext_vector_type(2))) float f32x2;
typedef __attribute__((ext_vector_type(4))) unsigned short ushort4v;
typedef __attribute__((ext_vector_type(4))) unsigned int uint4v;
typedef __attribute__((ext_vector_type(2))) unsigned int uint2v;

struct Tap { int i00, i01, i10, i11; float w00, w01, w10, w11; };

static __device__ __forceinline__ unsigned short f2bf(float f) {
    unsigned u = __builtin_bit_cast(unsigned, f);
    u = (u + 0x7fffu + ((u >> 16) & 1u)) >> 16;
    return (unsigned short)u;
}
static __device__ __forceinline__ float bf2f(unsigned short u) {
    return __builtin_bit_cast(float, (unsigned)u << 16);
}
// unpack 2 bf16 (packed in a dword) -> 2 f32: 1 shl + 1 and
static __device__ __forceinline__ f32x2 up2(unsigned u) {
    f32x2 r;
    r.x = __builtin_bit_cast(float, u << 16);
    r.y = __builtin_bit_cast(float, u & 0xffff0000u);
    return r;
}
// HW RNE pack (proven: absmax 0.03125 with this path end-to-end)
static __device__ __forceinline__ unsigned cvt_pk_bf16(float lo, float hi) {
    unsigned r;
    asm("v_cvt_pk_bf16_f32 %0, %1, %2" : "=v"(r) : "v"(lo), "v"(hi));
    return r;
}

// ---------------------------------------------------------------------------
// Build ALL per-resolution sampling tables in one launch (grid.y = size idx).
// AoS Tap (fp32 conv1_1 path) and AoS 32B records tabA[(kt*HW+p)*8] =
// {i00,i01,i10,i11, w00,w01,w10,w11}. Exact reference coordinate math.
// ---------------------------------------------------------------------------
struct TabPtrs { Tap* tab[5]; int* tabA[5]; };

__global__ void build_table_all(TabPtrs tp) {
    const int Ss[5] = {128, 64, 32, 16, 8};
    int si = blockIdx.y;
    int S = Ss[si];
    int idx = blockIdx.x * blockDim.x + threadIdx.x;
    int total = S * S * 9;
    if (idx >= total) return;
    Tap* __restrict__ tab  = tp.tab[si];
    int* __restrict__ tabA = tp.tabA[si];

    int k = idx % 9;
    int p = idx / 9;
    int y = p / S;
    int x = p - y * S;
    int HW = S * S;

    float c = 0.5f * (float)S - 0.5f;
    float theta = atan2f((float)x - c, (float)y - c);
    theta = fmodf(theta, TWO_PI_F);
    if (theta < 0.0f) theta += TWO_PI_F;
    theta = rintf(theta * 10000.0f) / 10000.0f;

    float offy = 0.0f, offx = 0.0f;
    if (k != 4) {
        int m = (k < 4) ? k : (k - 1);
        const float ayt[8] = { 1.f, 1.f,  1.f, 0.f,  0.f, -1.f, -1.f, -1.f };
        const float axt[8] = { 1.f, 0.f, -1.f, 1.f, -1.f,  1.f,  0.f, -1.f };
        float ang = theta + PI_4_F * (float)m;
        offy = cosf(ang) + ayt[m];
        offx = sinf(ang) + axt[m];
    }
    int ky = k / 3, kx = k - ky * 3;
    float py = (float)y - 1.0f + (float)ky + offy;
    float px = (float)x - 1.0f + (float)kx + offx;
    float fy0 = floorf(py), fx0 = floorf(px);
    float wy = py - fy0, wx = px - fx0;
    float fmaxc = (float)(S - 1);

    Tap t;
    {
        float yy = fy0, xx = fx0;
        bool v = (yy >= 0.f) && (yy <= fmaxc) && (xx >= 0.f) && (xx <= fmaxc);
        int yi = (int)fminf(fmaxf(yy, 0.f), fmaxc);
        int xi = (int)fminf(fmaxf(xx, 0.f), fmaxc);
        t.i00 = yi * S + xi;
        t.w00 = v ? (1.f - wy) * (1.f - wx) : 0.f;
    }
    {
        float yy = fy0, xx = fx0 + 1.0f;
        bool v = (yy >= 0.f) && (yy <= fmaxc) && (xx >= 0.f) && (xx <= fmaxc);
        int yi = (int)fminf(fmaxf(yy, 0.f), fmaxc);
        int xi = (int)fminf(fmaxf(xx, 0.f), fmaxc);
        t.i01 = yi * S + xi;
        t.w01 = v ? (1.f - wy) * wx : 0.f;
    }
    {
        float yy = fy0 + 1.0f, xx = fx0;
        bool v = (yy >= 0.f) && (yy <= fmaxc) && (xx >= 0.f) && (xx <= fmaxc);
        int yi = (int)fminf(fmaxf(yy, 0.f), fmaxc);
        int xi = (int)fminf(fmaxf(xx, 0.f), fmaxc);
        t.i10 = yi * S + xi;
        t.w10 = v ? wy * (1.f - wx) : 0.f;
    }
    {
        float yy = fy0 + 1.0f, xx = fx0 + 1.0f;
        bool v = (yy >= 0.f) && (yy <= fmaxc) && (xx >= 0.f) && (xx <= fmaxc);
        int yi = (int)fminf(fmaxf(yy, 0.f), fmaxc);
        int xi = (int)fminf(fmaxf(xx, 0.f), fmaxc);
        t.i11 = yi * S + xi;
        t.w11 = v ? wy * wx : 0.f;
    }
    tab[idx] = t;

    int rec = (k * HW + p) * 8;
    tabA[rec + 0] = t.i00;
    tabA[rec + 1] = t.i01;
    tabA[rec + 2] = t.i10;
    tabA[rec + 3] = t.i11;
    tabA[rec + 4] = __builtin_bit_cast(int, t.w00);
    tabA[rec + 5] = __builtin_bit_cast(int, t.w01);
    tabA[rec + 6] = __builtin_bit_cast(int, t.w10);
    tabA[rec + 7] = __builtin_bit_cast(int, t.w11);
}

// ---------------------------------------------------------------------------
// Pack ALL conv weights in one launch. fp32 w[O][C][9] -> bf16 fragment order
// wP[kb][o][32], TAP-MAJOR K: K = kt*C + c. Requires C % 32 == 0.
// ---------------------------------------------------------------------------
struct PackArgs {
    const float* w[12];
    unsigned short* wP[12];
    int O[12];
    int C[12];
    int tot[12];   // cumulative element counts
};

__global__ void pack_w_all(PackArgs pa, int grand) {
    int idx = blockIdx.x * blockDim.x + threadIdx.x;
    if (idx >= grand) return;
    int li = 0, base = 0;
#pragma unroll
    for (int i = 0; i < 11; ++i) {
        if (idx >= pa.tot[i]) { li = i + 1; base = pa.tot[i]; }
    }
    int rel = idx - base;
    int O = pa.O[li];
    int C = pa.C[li];
    int ksub = rel & 31;
    int kbo  = rel >> 5;
    int o  = kbo % O;
    int kb = kbo / O;
    int K = kb * 32 + ksub;
    int kt = K / C;
    int c  = K - kt * C;
    pa.wP[li][rel] = f2bf(pa.w[li][((size_t)o * C + c) * 9 + kt]);
}

// ---------------------------------------------------------------------------
// fp32 conv for conv1_1 only (C=3, fp32 NCHW input); output bf16 in blocked
// NC/8HW8 layout: act[b][o>>3][p][o&7].
// ---------------------------------------------------------------------------
__global__ __launch_bounds__(256) void dconv_f32_kernel(
    const float* __restrict__ x, const float* __restrict__ w,
    const Tap* __restrict__ tab, unsigned short* __restrict__ out,
    int C, int O, int HW)
{
    __shared__ float4 sTabRaw[64 * 9 * 2];
    __shared__ float  sS[9][64];
    __shared__ float  sW[9][64];

    const int tid = threadIdx.x;
    const int b  = blockIdx.z;
    const int o0 = blockIdx.y * 64;
    const int p0 = blockIdx.x * 64;
    const int C9 = C * 9;

    const float4* gt = (const float4*)(tab + (size_t)p0 * 9);
    for (int i = tid; i < 64 * 9 * 2; i += 256) sTabRaw[i] = gt[i];
    const Tap* sTab = (const Tap*)sTabRaw;
    __syncthreads();

    float acc[4][4];
#pragma unroll
    for (int i = 0; i < 4; ++i)
#pragma unroll
        for (int j = 0; j < 4; ++j) acc[i][j] = 0.f;

    const int to = tid >> 4;
    const int tn = tid & 15;
    const float* xb = x + (size_t)b * C * HW;

    for (int c = 0; c < C; ++c) {
        const float* xp = xb + (size_t)c * HW;
        for (int i = tid; i < 9 * 64; i += 256) {
            int k = i >> 6;
            int p = i & 63;
            Tap t = sTab[p * 9 + k];
            sS[k][p] = t.w00 * xp[t.i00] + t.w01 * xp[t.i01]
                     + t.w10 * xp[t.i10] + t.w11 * xp[t.i11];
        }
        for (int i = tid; i < 9 * 64; i += 256) {
            int k = i >> 6;
            int o = i & 63;
            sW[k][o] = w[(size_t)(o0 + o) * C9 + c * 9 + k];
        }
        __syncthreads();
#pragma unroll
        for (int k = 0; k < 9; ++k) {
            float4 wv = *(const float4*)&sW[k][to * 4];
            float4 sv = *(const float4*)&sS[k][tn * 4];
            acc[0][0] += wv.x * sv.x; acc[0][1] += wv.x * sv.y; acc[0][2] += wv.x * sv.z; acc[0][3] += wv.x * sv.w;
            acc[1][0] += wv.y * sv.x; acc[1][1] += wv.y * sv.y; acc[1][2] += wv.y * sv.z; acc[1][3] += wv.y * sv.w;
            acc[2][0] += wv.z * sv.x; acc[2][1] += wv.z * sv.y; acc[2][2] += wv.z * sv.z; acc[2][3] += wv.z * sv.w;
            acc[3][0] += wv.w * sv.x; acc[3][1] += wv.w * sv.y; acc[3][2] += wv.w * sv.z; acc[3][3] += wv.w * sv.w;
        }
        __syncthreads();
    }

    // blocked NC/8HW8 epilogue: o = o0 + to*4 + i (4 consecutive o per store)
    const int ob   = (o0 + to * 4) >> 3;
    const int osub = (to & 1) << 2;
#pragma unroll
    for (int j = 0; j < 4; ++j) {
        int p = p0 + tn * 4 + j;
        ushort4v v;
        v.x = f2bf(fmaxf(acc[0][j], 0.f));
        v.y = f2bf(fmaxf(acc[1][j], 0.f));
        v.z = f2bf(fmaxf(acc[2][j], 0.f));
        v.w = f2bf(fmaxf(acc[3][j], 0.f));
        *(ushort4v*)(out + (((size_t)b * (O >> 3) + ob) * HW + p) * 8 + osub) = v;
    }
}

// ---------------------------------------------------------------------------
// Round-9 MFMA deform-conv: round-8 body with the sampler kt-loop FULLY
// unrolled so the hoisted iiA[9] tap records are statically indexed and live
// in REGISTERS (round 8's `unroll 3` left kt runtime-varying -> iiA went to
// scratch: +73 MB spill traffic per dispatch, rule #20). kt==4 identity path
// kept (center tap: raw 16B copy). MFMA phase/epilogues unchanged (proven).
// ---------------------------------------------------------------------------
#define SPITCH 296   // ushorts per px row (288 + 8 pad; row = 592B, 16B aligned)

template<int BM>
__global__ __launch_bounds__(256, 4) void dconv_mfma(
    const unsigned short* __restrict__ x, const unsigned short* __restrict__ wP,
    const int* __restrict__ tabA, unsigned short* __restrict__ out,
    float* __restrict__ part,
    int C, int O, int HW, int Cchunk, int nChunks)
{
    __shared__ unsigned short sS[64 * SPITCH];    // 37888 B

    const int tid  = threadIdx.x;
    const int lane = tid & 63;
    const int wv   = tid >> 6;
    const int bz = blockIdx.z;
    const int b     = bz & 7;
    const int chunk = bz >> 3;

    // XCD swizzle: contiguous pixel-tile range per XCD (L2 locality for gathers)
    int bx = blockIdx.x;
    const int gx = gridDim.x;
    if ((gx & 7) == 0) { int g8 = gx >> 3; bx = (bx & 7) * g8 + (bx >> 3); }

    const int o0 = blockIdx.y * BM;
    const int p0 = bx * 64;
    const int c0 = chunk * Cchunk;
    const int nGroups = Cchunk >> 5;

    const int o0w = (BM == 128) ? wv * 32 : (wv >> 1) * 32;
    const int p0w = (BM == 128) ? 0       : (wv & 1) * 32;
    constexpr int MF = 2;
    constexpr int NF = (BM == 128) ? 4 : 2;

    f32x4 acc[MF][NF] = {};

    const unsigned short* xb = x + (size_t)b * C * HW;   // blocked plane
    const int quad = lane >> 4;
    const int l16  = lane & 15;
    const int* tq = tabA + (((size_t)(p0 + lane)) << 3); // lane's 32B record col
    unsigned short* srow = &sS[lane * SPITCH + (wv << 3)];
    const int HW8 = HW << 3;

    // ---- hoist tap index records: invariant across channel groups/chunks.
    // Statically indexed everywhere below (full unroll) -> stays in VGPRs.
    int4 iiA[9];
#pragma unroll
    for (int kt = 0; kt < 9; ++kt)
        iiA[kt] = *(const int4*)(tq + kt * HW8);

    for (int g = 0; g < nGroups; ++g) {
        const int cg = c0 + g * 32;
        // wave's 8-channel block: cb = cg/8 + wv
        const unsigned short* xcb = xb + ((((size_t)(cg >> 3) + wv) * HW) << 3);

        // ---- sample: 9 taps x 8 channels per wave (FULL unroll: static iiA)
#pragma unroll
        for (int kt = 0; kt < 9; ++kt) {
            int4 ii = iiA[kt];
            if (kt == 4) {
                // center tap is identity (w00=1, i00=p): raw 16B copy, exact
                *(uint4v*)(srow + kt * 32) = *(const uint4v*)(xcb + ((size_t)ii.x << 3));
            } else {
                int4 iw = *(const int4*)(tq + kt * HW8 + 4);
                float w00 = __builtin_bit_cast(float, iw.x);
                float w01 = __builtin_bit_cast(float, iw.y);
                float w10 = __builtin_bit_cast(float, iw.z);
                float w11 = __builtin_bit_cast(float, iw.w);
                uint4v g00 = *(const uint4v*)(xcb + ((size_t)ii.x << 3));
                uint4v g01 = *(const uint4v*)(xcb + ((size_t)ii.y << 3));
                uint4v g10 = *(const uint4v*)(xcb + ((size_t)ii.z << 3));
                uint4v g11 = *(const uint4v*)(xcb + ((size_t)ii.w << 3));
                uint4v pk;
#pragma unroll
                for (int wd = 0; wd < 4; ++wd) {
                    f32x2 s = up2(g00[wd]) * w00 + up2(g01[wd]) * w01
                            + up2(g10[wd]) * w10 + up2(g11[wd]) * w11;
                    pk[wd] = cvt_pk_bf16(s.x, s.y);
                }
                *(uint4v*)(srow + kt * 32) = pk;
            }
        }
        __syncthreads();

        // ---- 9 MFMA k-steps; K-tile for tap kt is kb = (kt*C + cg)/32
#pragma unroll 3
        for (int kt = 0; kt < 9; ++kt) {
            const int kb = (kt * C + cg) >> 5;
            short8 afr[MF], bfr[NF];
#pragma unroll
            for (int mf = 0; mf < MF; ++mf) {
                int orow = o0 + o0w + mf * 16 + l16;
                afr[mf] = *(const short8*)(wP + (((size_t)kb * O + orow) << 5) + (quad << 3));
            }
#pragma unroll
            for (int nf = 0; nf < NF; ++nf) {
                int prow = p0w + nf * 16 + l16;
                bfr[nf] = *(const short8*)(&sS[prow * SPITCH + kt * 32 + (quad << 3)]);
            }
#pragma unroll
            for (int mf = 0; mf < MF; ++mf)
#pragma unroll
                for (int nf = 0; nf < NF; ++nf)
                    acc[mf][nf] = __builtin_amdgcn_mfma_f32_16x16x32_bf16(afr[mf], bfr[nf], acc[mf][nf], 0, 0, 0);
        }
        __syncthreads();
    }

    const int O8 = O >> 3;
    if (nChunks == 1) {
#pragma unroll
        for (int mf = 0; mf < MF; ++mf)
#pragma unroll
            for (int nf = 0; nf < NF; ++nf) {
                int o = o0 + o0w + mf * 16 + (quad << 2);        // 4 consecutive o
                int p = p0 + p0w + nf * 16 + l16;
                size_t base = (((size_t)b * O8 + (o >> 3)) * HW + p) * 8 + (o & 7);
                uint2v pk2;
                pk2.x = cvt_pk_bf16(fmaxf(acc[mf][nf][0], 0.f), fmaxf(acc[mf][nf][1], 0.f));
                pk2.y = cvt_pk_bf16(fmaxf(acc[mf][nf][2], 0.f), fmaxf(acc[mf][nf][3], 0.f));
                *(uint2v*)(out + base) = pk2;
            }
    } else {
        float* pb = part + (size_t)chunk * 8 * O * HW;
#pragma unroll
        for (int mf = 0; mf < MF; ++mf)
#pragma unroll
            for (int nf = 0; nf < NF; ++nf) {
                int o = o0 + o0w + mf * 16 + (quad << 2);
                int p = p0 + p0w + nf * 16 + l16;
                size_t base = (((size_t)b * O8 + (o >> 3)) * HW + p) * 8 + (o & 7);
                *(f32x4*)(pb + base) = acc[mf][nf];
            }
    }
}

// sum partial chunks + ReLU -> bf16 activation (layout-agnostic elementwise)
__global__ void reduce_relu_kernel(const float* __restrict__ part,
                                   unsigned short* __restrict__ out,
                                   int per4, int nChunks)
{
    int idx = blockIdx.x * blockDim.x + threadIdx.x;
    if (idx >= per4) return;
    const float4* p4 = (const float4*)part;
    float4 s = p4[idx];
    for (int ch = 1; ch < nChunks; ++ch) {
        float4 v = p4[(size_t)ch * per4 + idx];
        s.x += v.x; s.y += v.y; s.z += v.z; s.w += v.w;
    }
    ushort4v r;
    r.x = f2bf(fmaxf(s.x, 0.f)); r.y = f2bf(fmaxf(s.y, 0.f));
    r.z = f2bf(fmaxf(s.z, 0.f)); r.w = f2bf(fmaxf(s.w, 0.f));
    ((ushort4v*)out)[idx] = r;
}

// sum partial chunks + ReLU + 2x2 maxpool, blocked NC/8HW8 layout
__global__ void reduce_relu_pool_kernel(const float* __restrict__ part,
                                        unsigned short* __restrict__ out,
                                        int S, int per, int nChunks, int total)
{
    int idx = blockIdx.x * blockDim.x + threadIdx.x;
    if (idx >= total) return;
    int Sl = 31 - __clz(S);          // log2 S (S pow2)
    int W2 = S >> 1;
    int c8 = idx & 7;
    int t  = idx >> 3;
    int x2 = t & (W2 - 1); t >>= (Sl - 1);
    int y2 = t & (W2 - 1); t >>= (Sl - 1);
    // t = b*(C/8) + cb : plane-row index, used directly
    size_t base = (((size_t)t * S + 2 * y2) * S + 2 * x2) * 8 + c8;
    size_t dX = 8;                    // x+1
    size_t dY = (size_t)S * 8;        // y+1
    float s0 = 0.f, s1 = 0.f, s2 = 0.f, s3 = 0.f;
    for (int ch = 0; ch < nChunks; ++ch) {
        const float* p = part + (size_t)ch * per + base;
        s0 += p[0]; s1 += p[dX]; s2 += p[dY]; s3 += p[dY + dX];
    }
    out[idx] = f2bf(fmaxf(fmaxf(fmaxf(s0, s1), fmaxf(s2, s3)), 0.f));
}

// bf16 2x2 maxpool, blocked NC/8HW8 layout (post-ReLU values; conversions exact)
__global__ void maxpool_kernel(const unsigned short* __restrict__ in,
                               unsigned short* __restrict__ out,
                               int S, int total)
{
    int idx = blockIdx.x * blockDim.x + threadIdx.x;
    if (idx >= total) return;
    int Sl = 31 - __clz(S);
    int W2 = S >> 1;
    int c8 = idx & 7;
    int t  = idx >> 3;
    int x2 = t & (W2 - 1); t >>= (Sl - 1);
    int y2 = t & (W2 - 1); t >>= (Sl - 1);
    size_t base = (((size_t)t * S + 2 * y2) * S + 2 * x2) * 8 + c8;
    size_t dY = (size_t)S * 8;
    const unsigned short* p = in + base;
    float m = fmaxf(fmaxf(bf2f(p[0]), bf2f(p[8])), fmaxf(bf2f(p[dY]), bf2f(p[dY + 8])));
    out[idx] = f2bf(m);
}

// 4x4 avg pool, blocked bf16 (b,64cb,16px,8) in -> fp32 pooled[b][512] out
__global__ void avgpool_kernel(const unsigned short* __restrict__ in,
                               float* __restrict__ out, int total)
{
    int idx = blockIdx.x * blockDim.x + threadIdx.x;
    if (idx >= total) return;
    int b = idx >> 9;
    int c = idx & 511;
    int cb = c >> 3, c8 = c & 7;
    const unsigned short* p = in + (((size_t)(b * 64 + cb) * 16) << 3) + c8;
    float s = 0.f;
#pragma unroll
    for (int i = 0; i < 16; ++i) s += bf2f(p[i * 8]);
    out[idx] = s * (1.0f / 16.0f);
}

__global__ __launch_bounds__(256) void fc_kernel(
    const float* __restrict__ x, const float* __restrict__ w,
    const float* __restrict__ bias, float* __restrict__ out,
    int K, int O, int relu)
{
    int o = blockIdx.x;
    float acc[8] = {0.f,0.f,0.f,0.f,0.f,0.f,0.f,0.f};
    const float* wr = w + (size_t)o * K;
    for (int k = threadIdx.x; k < K; k += 256) {
        float wv = wr[k];
#pragma unroll
        for (int b = 0; b < 8; ++b) acc[b] += wv * x[(size_t)b * K + k];
    }
    __shared__ float red[8][256];
#pragma unroll
    for (int b = 0; b < 8; ++b) red[b][threadIdx.x] = acc[b];
    __syncthreads();
    for (int s = 128; s > 0; s >>= 1) {
        if (threadIdx.x < s) {
#pragma unroll
            for (int b = 0; b < 8; ++b) red[b][threadIdx.x] += red[b][threadIdx.x + s];
        }
        __syncthreads();
    }
    if (threadIdx.x < 8) {
        float v = red[threadIdx.x][0] + bias[o];
        if (relu) v = fmaxf(v, 0.f);
        out[(size_t)threadIdx.x * O + o] = v;
    }
}

// ---------------------------------------------------------------------------
// Host orchestration. Round-7 layout/grids (proven 700 us) + fused prologue.
// ---------------------------------------------------------------------------
extern "C" void kernel_launch(void* const* d_in, const int* in_sizes, int n_in,
                              void* d_out, int out_size, void* d_ws, size_t ws_size,
                              hipStream_t stream) {
    const float* x    = (const float*)d_in[0];
    const float* wf[13];
    for (int i = 0; i < 13; ++i) wf[i] = (const float*)d_in[1 + i];
    const float* fc1w = (const float*)d_in[14];
    const float* fc1b = (const float*)d_in[15];
    const float* fc2w = (const float*)d_in[16];
    const float* fc2b = (const float*)d_in[17];
    const float* fc3w = (const float*)d_in[18];
    const float* fc3b = (const float*)d_in[19];
    float* out = (float*)d_out;

    char* ws = (char*)d_ws;
    auto alloc = [&](size_t bytes) -> char* {
        char* p = ws;
        ws += (bytes + 255) & ~(size_t)255;
        return p;
    };

    const int sizes[5] = {128, 64, 32, 16, 8};
    Tap* tabs[5];
    int* tabAs[5];
    for (int i = 0; i < 5; ++i) {
        int HW = sizes[i] * sizes[i];
        tabs[i]  = (Tap*)alloc((size_t)HW * 9 * sizeof(Tap));
        tabAs[i] = (int*)alloc((size_t)HW * 9 * 8 * sizeof(int));
    }
    unsigned short* actA = (unsigned short*)alloc((size_t)8 * 64 * 128 * 128 * 2);
    unsigned short* actB = (unsigned short*)alloc((size_t)8 * 64 * 128 * 128 * 2);
    float* partial = (float*)alloc((size_t)2 * 8 * 128 * 4096 * sizeof(float)); // 33.55 MB
    const int Cs[13] = {3, 64, 64, 128, 128, 256, 256, 256, 512, 512, 512, 512, 512};
    const int Os[13] = {64, 64, 128, 128, 256, 256, 256, 512, 512, 512, 512, 512, 512};
    unsigned short* wPk[13];
    wPk[0] = nullptr;
    for (int i = 1; i < 13; ++i)
        wPk[i] = (unsigned short*)alloc((size_t)Os[i] * Cs[i] * 9 * sizeof(unsigned short));
    float* pooled = (float*)alloc((size_t)8 * 512 * sizeof(float));
    float* fcb1 = (float*)alloc((size_t)8 * 4096 * sizeof(float));
    float* fcb2 = (float*)alloc((size_t)8 * 4096 * sizeof(float));

    // fused table build (5 sizes, grid.y = size index)
    {
        TabPtrs tp;
        for (int i = 0; i < 5; ++i) { tp.tab[i] = tabs[i]; tp.tabA[i] = tabAs[i]; }
        dim3 grid((128 * 128 * 9 + 255) / 256, 5);
        build_table_all<<<grid, 256, 0, stream>>>(tp);
    }
    // fused weight pack (12 layers)
    {
        PackArgs pa;
        int cum = 0;
        for (int i = 0; i < 12; ++i) {
            pa.w[i]  = wf[i + 1];
            pa.wP[i] = wPk[i + 1];
            pa.O[i]  = Os[i + 1];
            pa.C[i]  = Cs[i + 1];
            cum += Os[i + 1] * Cs[i + 1] * 9;
            pa.tot[i] = cum;
        }
        pack_w_all<<<(cum + 255) / 256, 256, 0, stream>>>(pa, cum);
    }

    auto convM = [&](const unsigned short* in, const unsigned short* wp, int* tabA,
                     unsigned short* o, int C, int O, int S, int nCh, int BM, bool leavePartial) {
        int HW = S * S;
        int Cchunk = C / nCh;
        if (BM == 64) {
            dim3 grid(HW / 64, O / 64, 8 * nCh);
            dconv_mfma<64><<<grid, 256, 0, stream>>>(in, wp, tabA, o, partial, C, O, HW, Cchunk, nCh);
        } else {
            dim3 grid(HW / 64, O / 128, 8 * nCh);
            dconv_mfma<128><<<grid, 256, 0, stream>>>(in, wp, tabA, o, partial, C, O, HW, Cchunk, nCh);
        }
        if (nCh > 1 && !leavePartial) {
            int per4 = 8 * O * HW / 4;
            reduce_relu_kernel<<<(per4 + 255) / 256, 256, 0, stream>>>(partial, o, per4, nCh);
        }
    };
    auto fusedPool = [&](unsigned short* o, int C, int H, int nCh) {
        int per = 8 * C * H * H;
        int total = per / 4;
        reduce_relu_pool_kernel<<<(total + 255) / 256, 256, 0, stream>>>(partial, o, H, per, nCh, total);
    };

    // conv1_1: fp32 input path (C=3) -> bf16 actA (blocked NC/8HW8)
    {
        dim3 grid(128 * 128 / 64, 1, 8);
        dconv_f32_kernel<<<grid, 256, 0, stream>>>(x, wf[0], tabs[0], actA, 3, 64, 128 * 128);
    }
    convM(actA, wPk[1],  tabAs[0], actB, 64,  64,  128, 1, 64, false);   // conv1_2 -> actB
    {
        int total = 8 * 64 * 64 * 64;
        maxpool_kernel<<<(total + 255) / 256, 256, 0, stream>>>(actB, actA, 128, total);
    }
    convM(actA, wPk[2],  tabAs[1], actB, 64,  128, 64, 2, 128, false);   // conv2_1 -> actB
    convM(actB, wPk[3],  tabAs[1], nullptr, 128, 128, 64, 2, 128, true); // conv2_2 -> partial
    fusedPool(actA, 128, 64, 2);                                         // -> actA (128ch @32^2)
    convM(actA, wPk[4],  tabAs[2], actB, 128, 256, 32, 4, 128, false);   // conv3_1 -> actB
    convM(actB, wPk[5],  tabAs[2], actA, 256, 256, 32, 4, 128, false);   // conv3_2 -> actA
    convM(actA, wPk[6],  tabAs[2], nullptr, 256, 256, 32, 4, 128, true); // conv3_3 -> partial
    fusedPool(actB, 256, 32, 4);                                         // -> actB (256ch @16^2)
    convM(actB, wPk[7],  tabAs[3], actA, 256, 512, 16, 8, 128, false);   // conv4_1 -> actA
    convM(actA, wPk[8],  tabAs[3], actB, 512, 512, 16, 8, 128, false);   // conv4_2 -> actB
    convM(actB, wPk[9],  tabAs[3], nullptr, 512, 512, 16, 8, 128, true); // conv4_3 -> partial
    fusedPool(actA, 512, 16, 8);                                         // -> actA (512ch @8^2)
    convM(actA, wPk[10], tabAs[4], actB, 512, 512, 8, 16, 64, false);    // conv5_1 -> actB
    convM(actB, wPk[11], tabAs[4], actA, 512, 512, 8, 16, 64, false);    // conv5_2 -> actA
    convM(actA, wPk[12], tabAs[4], nullptr, 512, 512, 8, 16, 64, true);  // conv5_3 -> partial
    fusedPool(actB, 512, 8, 16);                                         // -> actB (512ch @4^2)

    avgpool_kernel<<<(4096 + 255) / 256, 256, 0, stream>>>(actB, pooled, 8 * 512);

    fc_kernel<<<4096, 256, 0, stream>>>(pooled, fc1w, fc1b, fcb1, 512,  4096, 1);
    fc_kernel<<<4096, 256, 0, stream>>>(fcb1,   fc2w, fc2b, fcb2, 4096, 4096, 1);
    fc_kernel<<<30,   256, 0, stream>>>(fcb2,   fc3w, fc3b, out,  4096, 30,   0);
}

// Round 10
// 680.176 us; speedup vs baseline: 1.1740x; 1.1740x over previous
//
#include <hip/hip_runtime.h>
#include <math.h>

#define TWO_PI_F 6.283185307179586f
#define PI_4_F   0.7853981633974483f

typedef __attribute__((ext_vector_type(8))) short short8;
typedef __attribute__((ext_vector_type(4))) float f32x4;
typedef __attribute__((ext_vector_type(2))) float f32x2;
typedef __attribute__((ext_vector_type(4))) unsigned short ushort4v;
typedef __attribute__((ext_vector_type(4))) unsigned int uint4v;
typedef __attribute__((ext_vector_type(2))) unsigned int uint2v;

struct Tap { int i00, i01, i10, i11; float w00, w01, w10, w11; };

static __device__ __forceinline__ unsigned short f2bf(float f) {
    unsigned u = __builtin_bit_cast(unsigned, f);
    u = (u + 0x7fffu + ((u >> 16) & 1u)) >> 16;
    return (unsigned short)u;
}
static __device__ __forceinline__ float bf2f(unsigned short u) {
    return __builtin_bit_cast(float, (unsigned)u << 16);
}
// unpack 2 bf16 (packed in a dword) -> 2 f32: 1 shl + 1 and
static __device__ __forceinline__ f32x2 up2(unsigned u) {
    f32x2 r;
    r.x = __builtin_bit_cast(float, u << 16);
    r.y = __builtin_bit_cast(float, u & 0xffff0000u);
    return r;
}
// HW RNE pack (proven: absmax 0.03125 with this path end-to-end)
static __device__ __forceinline__ unsigned cvt_pk_bf16(float lo, float hi) {
    unsigned r;
    asm("v_cvt_pk_bf16_f32 %0, %1, %2" : "=v"(r) : "v"(lo), "v"(hi));
    return r;
}

// ---------------------------------------------------------------------------
// Build ALL per-resolution sampling tables in one launch (grid.y = size idx).
// AoS Tap (fp32 conv1_1 path) and AoS 32B records tabA[(kt*HW+p)*8] =
// {i00,i01,i10,i11, w00,w01,w10,w11}. Exact reference coordinate math.
// ---------------------------------------------------------------------------
struct TabPtrs { Tap* tab[5]; int* tabA[5]; };

__global__ void build_table_all(TabPtrs tp) {
    const int Ss[5] = {128, 64, 32, 16, 8};
    int si = blockIdx.y;
    int S = Ss[si];
    int idx = blockIdx.x * blockDim.x + threadIdx.x;
    int total = S * S * 9;
    if (idx >= total) return;
    Tap* __restrict__ tab  = tp.tab[si];
    int* __restrict__ tabA = tp.tabA[si];

    int k = idx % 9;
    int p = idx / 9;
    int y = p / S;
    int x = p - y * S;
    int HW = S * S;

    float c = 0.5f * (float)S - 0.5f;
    float theta = atan2f((float)x - c, (float)y - c);
    theta = fmodf(theta, TWO_PI_F);
    if (theta < 0.0f) theta += TWO_PI_F;
    theta = rintf(theta * 10000.0f) / 10000.0f;

    float offy = 0.0f, offx = 0.0f;
    if (k != 4) {
        int m = (k < 4) ? k : (k - 1);
        const float ayt[8] = { 1.f, 1.f,  1.f, 0.f,  0.f, -1.f, -1.f, -1.f };
        const float axt[8] = { 1.f, 0.f, -1.f, 1.f, -1.f,  1.f,  0.f, -1.f };
        float ang = theta + PI_4_F * (float)m;
        offy = cosf(ang) + ayt[m];
        offx = sinf(ang) + axt[m];
    }
    int ky = k / 3, kx = k - ky * 3;
    float py = (float)y - 1.0f + (float)ky + offy;
    float px = (float)x - 1.0f + (float)kx + offx;
    float fy0 = floorf(py), fx0 = floorf(px);
    float wy = py - fy0, wx = px - fx0;
    float fmaxc = (float)(S - 1);

    Tap t;
    {
        float yy = fy0, xx = fx0;
        bool v = (yy >= 0.f) && (yy <= fmaxc) && (xx >= 0.f) && (xx <= fmaxc);
        int yi = (int)fminf(fmaxf(yy, 0.f), fmaxc);
        int xi = (int)fminf(fmaxf(xx, 0.f), fmaxc);
        t.i00 = yi * S + xi;
        t.w00 = v ? (1.f - wy) * (1.f - wx) : 0.f;
    }
    {
        float yy = fy0, xx = fx0 + 1.0f;
        bool v = (yy >= 0.f) && (yy <= fmaxc) && (xx >= 0.f) && (xx <= fmaxc);
        int yi = (int)fminf(fmaxf(yy, 0.f), fmaxc);
        int xi = (int)fminf(fmaxf(xx, 0.f), fmaxc);
        t.i01 = yi * S + xi;
        t.w01 = v ? (1.f - wy) * wx : 0.f;
    }
    {
        float yy = fy0 + 1.0f, xx = fx0;
        bool v = (yy >= 0.f) && (yy <= fmaxc) && (xx >= 0.f) && (xx <= fmaxc);
        int yi = (int)fminf(fmaxf(yy, 0.f), fmaxc);
        int xi = (int)fminf(fmaxf(xx, 0.f), fmaxc);
        t.i10 = yi * S + xi;
        t.w10 = v ? wy * (1.f - wx) : 0.f;
    }
    {
        float yy = fy0 + 1.0f, xx = fx0 + 1.0f;
        bool v = (yy >= 0.f) && (yy <= fmaxc) && (xx >= 0.f) && (xx <= fmaxc);
        int yi = (int)fminf(fmaxf(yy, 0.f), fmaxc);
        int xi = (int)fminf(fmaxf(xx, 0.f), fmaxc);
        t.i11 = yi * S + xi;
        t.w11 = v ? wy * wx : 0.f;
    }
    tab[idx] = t;

    int rec = (k * HW + p) * 8;
    tabA[rec + 0] = t.i00;
    tabA[rec + 1] = t.i01;
    tabA[rec + 2] = t.i10;
    tabA[rec + 3] = t.i11;
    tabA[rec + 4] = __builtin_bit_cast(int, t.w00);
    tabA[rec + 5] = __builtin_bit_cast(int, t.w01);
    tabA[rec + 6] = __builtin_bit_cast(int, t.w10);
    tabA[rec + 7] = __builtin_bit_cast(int, t.w11);
}

// ---------------------------------------------------------------------------
// Pack ALL conv weights in one launch. fp32 w[O][C][9] -> bf16 fragment order
// wP[kb][o][32], TAP-MAJOR K: K = kt*C + c. Requires C % 32 == 0.
// ---------------------------------------------------------------------------
struct PackArgs {
    const float* w[12];
    unsigned short* wP[12];
    int O[12];
    int C[12];
    int tot[12];   // cumulative element counts
};

__global__ void pack_w_all(PackArgs pa, int grand) {
    int idx = blockIdx.x * blockDim.x + threadIdx.x;
    if (idx >= grand) return;
    int li = 0, base = 0;
#pragma unroll
    for (int i = 0; i < 11; ++i) {
        if (idx >= pa.tot[i]) { li = i + 1; base = pa.tot[i]; }
    }
    int rel = idx - base;
    int O = pa.O[li];
    int C = pa.C[li];
    int ksub = rel & 31;
    int kbo  = rel >> 5;
    int o  = kbo % O;
    int kb = kbo / O;
    int K = kb * 32 + ksub;
    int kt = K / C;
    int c  = K - kt * C;
    pa.wP[li][rel] = f2bf(pa.w[li][((size_t)o * C + c) * 9 + kt]);
}

// ---------------------------------------------------------------------------
// fp32 conv for conv1_1 only (C=3, fp32 NCHW input); output bf16 in blocked
// NC/8HW8 layout: act[b][o>>3][p][o&7].
// ---------------------------------------------------------------------------
__global__ __launch_bounds__(256) void dconv_f32_kernel(
    const float* __restrict__ x, const float* __restrict__ w,
    const Tap* __restrict__ tab, unsigned short* __restrict__ out,
    int C, int O, int HW)
{
    __shared__ float4 sTabRaw[64 * 9 * 2];
    __shared__ float  sS[9][64];
    __shared__ float  sW[9][64];

    const int tid = threadIdx.x;
    const int b  = blockIdx.z;
    const int o0 = blockIdx.y * 64;
    const int p0 = blockIdx.x * 64;
    const int C9 = C * 9;

    const float4* gt = (const float4*)(tab + (size_t)p0 * 9);
    for (int i = tid; i < 64 * 9 * 2; i += 256) sTabRaw[i] = gt[i];
    const Tap* sTab = (const Tap*)sTabRaw;
    __syncthreads();

    float acc[4][4];
#pragma unroll
    for (int i = 0; i < 4; ++i)
#pragma unroll
        for (int j = 0; j < 4; ++j) acc[i][j] = 0.f;

    const int to = tid >> 4;
    const int tn = tid & 15;
    const float* xb = x + (size_t)b * C * HW;

    for (int c = 0; c < C; ++c) {
        const float* xp = xb + (size_t)c * HW;
        for (int i = tid; i < 9 * 64; i += 256) {
            int k = i >> 6;
            int p = i & 63;
            Tap t = sTab[p * 9 + k];
            sS[k][p] = t.w00 * xp[t.i00] + t.w01 * xp[t.i01]
                     + t.w10 * xp[t.i10] + t.w11 * xp[t.i11];
        }
        for (int i = tid; i < 9 * 64; i += 256) {
            int k = i >> 6;
            int o = i & 63;
            sW[k][o] = w[(size_t)(o0 + o) * C9 + c * 9 + k];
        }
        __syncthreads();
#pragma unroll
        for (int k = 0; k < 9; ++k) {
            float4 wv = *(const float4*)&sW[k][to * 4];
            float4 sv = *(const float4*)&sS[k][tn * 4];
            acc[0][0] += wv.x * sv.x; acc[0][1] += wv.x * sv.y; acc[0][2] += wv.x * sv.z; acc[0][3] += wv.x * sv.w;
            acc[1][0] += wv.y * sv.x; acc[1][1] += wv.y * sv.y; acc[1][2] += wv.y * sv.z; acc[1][3] += wv.y * sv.w;
            acc[2][0] += wv.z * sv.x; acc[2][1] += wv.z * sv.y; acc[2][2] += wv.z * sv.z; acc[2][3] += wv.z * sv.w;
            acc[3][0] += wv.w * sv.x; acc[3][1] += wv.w * sv.y; acc[3][2] += wv.w * sv.z; acc[3][3] += wv.w * sv.w;
        }
        __syncthreads();
    }

    // blocked NC/8HW8 epilogue: o = o0 + to*4 + i (4 consecutive o per store)
    const int ob   = (o0 + to * 4) >> 3;
    const int osub = (to & 1) << 2;
#pragma unroll
    for (int j = 0; j < 4; ++j) {
        int p = p0 + tn * 4 + j;
        ushort4v v;
        v.x = f2bf(fmaxf(acc[0][j], 0.f));
        v.y = f2bf(fmaxf(acc[1][j], 0.f));
        v.z = f2bf(fmaxf(acc[2][j], 0.f));
        v.w = f2bf(fmaxf(acc[3][j], 0.f));
        *(ushort4v*)(out + (((size_t)b * (O >> 3) + ob) * HW + p) * 8 + osub) = v;
    }
}

// ---------------------------------------------------------------------------
// Round-7-EXACT MFMA deform-conv (proven 53.6us conv1_2 / 700us total,
// absmax 0.03125). The r8/r9 tab-hoist variants both spilled to scratch
// (counter-proven: +60-73MB FETCH/WRITE per dispatch); this body reloads the
// 2x16B tab record per (group, tap) -- L1/L2-resident, nGroups<=2 reuse.
// Blocked NC/8HW8 activations, 4x16B gathers per 8-channel sample, cvt_pk
// pack, LDS-staged B-fragments, XCD pixel-tile swizzle.
// ---------------------------------------------------------------------------
#define SPITCH 296   // ushorts per px row (288 + 8 pad; row = 592B, 16B aligned)

template<int BM>
__global__ __launch_bounds__(256, 4) void dconv_mfma(
    const unsigned short* __restrict__ x, const unsigned short* __restrict__ wP,
    const int* __restrict__ tabA, unsigned short* __restrict__ out,
    float* __restrict__ part,
    int C, int O, int HW, int Cchunk, int nChunks)
{
    __shared__ unsigned short sS[64 * SPITCH];    // 37888 B

    const int tid  = threadIdx.x;
    const int lane = tid & 63;
    const int wv   = tid >> 6;
    const int bz = blockIdx.z;
    const int b     = bz & 7;
    const int chunk = bz >> 3;

    // XCD swizzle: contiguous pixel-tile range per XCD (L2 locality for gathers)
    int bx = blockIdx.x;
    const int gx = gridDim.x;
    if ((gx & 7) == 0) { int g8 = gx >> 3; bx = (bx & 7) * g8 + (bx >> 3); }

    const int o0 = blockIdx.y * BM;
    const int p0 = bx * 64;
    const int c0 = chunk * Cchunk;
    const int nGroups = Cchunk >> 5;

    const int o0w = (BM == 128) ? wv * 32 : (wv >> 1) * 32;
    const int p0w = (BM == 128) ? 0       : (wv & 1) * 32;
    constexpr int MF = 2;
    constexpr int NF = (BM == 128) ? 4 : 2;

    f32x4 acc[MF][NF] = {};

    const unsigned short* xb = x + (size_t)b * C * HW;   // blocked plane
    const int quad = lane >> 4;
    const int l16  = lane & 15;
    const int* tq = tabA + (((size_t)(p0 + lane)) << 3); // lane's 32B record col
    unsigned short* srow = &sS[lane * SPITCH + (wv << 3)];

    for (int g = 0; g < nGroups; ++g) {
        const int cg = c0 + g * 32;
        // wave's 8-channel block: cb = cg/8 + wv
        const unsigned short* xcb = xb + ((((size_t)(cg >> 3) + wv) * HW) << 3);

        // ---- sample: 9 taps x 8 channels per wave; per tap: 2x16B tab loads
        //      + 4x16B activation gathers (contiguous across lanes)
#pragma unroll 3
        for (int kt = 0; kt < 9; ++kt) {
            const int* tp = tq + kt * (HW << 3);
            int4 ii = *(const int4*)tp;
            int4 iw = *(const int4*)(tp + 4);
            float w00 = __builtin_bit_cast(float, iw.x);
            float w01 = __builtin_bit_cast(float, iw.y);
            float w10 = __builtin_bit_cast(float, iw.z);
            float w11 = __builtin_bit_cast(float, iw.w);
            uint4v g00 = *(const uint4v*)(xcb + ((size_t)ii.x << 3));
            uint4v g01 = *(const uint4v*)(xcb + ((size_t)ii.y << 3));
            uint4v g10 = *(const uint4v*)(xcb + ((size_t)ii.z << 3));
            uint4v g11 = *(const uint4v*)(xcb + ((size_t)ii.w << 3));
            uint4v pk;
#pragma unroll
            for (int wd = 0; wd < 4; ++wd) {
                f32x2 s = up2(g00[wd]) * w00 + up2(g01[wd]) * w01
                        + up2(g10[wd]) * w10 + up2(g11[wd]) * w11;
                pk[wd] = cvt_pk_bf16(s.x, s.y);
            }
            *(uint4v*)(srow + kt * 32) = pk;
        }
        __syncthreads();

        // ---- 9 MFMA k-steps; K-tile for tap kt is kb = (kt*C + cg)/32
#pragma unroll 3
        for (int kt = 0; kt < 9; ++kt) {
            const int kb = (kt * C + cg) >> 5;
            short8 afr[MF], bfr[NF];
#pragma unroll
            for (int mf = 0; mf < MF; ++mf) {
                int orow = o0 + o0w + mf * 16 + l16;
                afr[mf] = *(const short8*)(wP + (((size_t)kb * O + orow) << 5) + (quad << 3));
            }
#pragma unroll
            for (int nf = 0; nf < NF; ++nf) {
                int prow = p0w + nf * 16 + l16;
                bfr[nf] = *(const short8*)(&sS[prow * SPITCH + kt * 32 + (quad << 3)]);
            }
#pragma unroll
            for (int mf = 0; mf < MF; ++mf)
#pragma unroll
                for (int nf = 0; nf < NF; ++nf)
                    acc[mf][nf] = __builtin_amdgcn_mfma_f32_16x16x32_bf16(afr[mf], bfr[nf], acc[mf][nf], 0, 0, 0);
        }
        __syncthreads();
    }

    const int O8 = O >> 3;
    if (nChunks == 1) {
#pragma unroll
        for (int mf = 0; mf < MF; ++mf)
#pragma unroll
            for (int nf = 0; nf < NF; ++nf) {
                int o = o0 + o0w + mf * 16 + (quad << 2);        // 4 consecutive o
                int p = p0 + p0w + nf * 16 + l16;
                size_t base = (((size_t)b * O8 + (o >> 3)) * HW + p) * 8 + (o & 7);
                uint2v pk2;
                pk2.x = cvt_pk_bf16(fmaxf(acc[mf][nf][0], 0.f), fmaxf(acc[mf][nf][1], 0.f));
                pk2.y = cvt_pk_bf16(fmaxf(acc[mf][nf][2], 0.f), fmaxf(acc[mf][nf][3], 0.f));
                *(uint2v*)(out + base) = pk2;
            }
    } else {
        float* pb = part + (size_t)chunk * 8 * O * HW;
#pragma unroll
        for (int mf = 0; mf < MF; ++mf)
#pragma unroll
            for (int nf = 0; nf < NF; ++nf) {
                int o = o0 + o0w + mf * 16 + (quad << 2);
                int p = p0 + p0w + nf * 16 + l16;
                size_t base = (((size_t)b * O8 + (o >> 3)) * HW + p) * 8 + (o & 7);
                *(f32x4*)(pb + base) = acc[mf][nf];
            }
    }
}

// sum partial chunks + ReLU -> bf16 activation (layout-agnostic elementwise)
__global__ void reduce_relu_kernel(const float* __restrict__ part,
                                   unsigned short* __restrict__ out,
                                   int per4, int nChunks)
{
    int idx = blockIdx.x * blockDim.x + threadIdx.x;
    if (idx >= per4) return;
    const float4* p4 = (const float4*)part;
    float4 s = p4[idx];
    for (int ch = 1; ch < nChunks; ++ch) {
        float4 v = p4[(size_t)ch * per4 + idx];
        s.x += v.x; s.y += v.y; s.z += v.z; s.w += v.w;
    }
    ushort4v r;
    r.x = f2bf(fmaxf(s.x, 0.f)); r.y = f2bf(fmaxf(s.y, 0.f));
    r.z = f2bf(fmaxf(s.z, 0.f)); r.w = f2bf(fmaxf(s.w, 0.f));
    ((ushort4v*)out)[idx] = r;
}

// sum partial chunks + ReLU + 2x2 maxpool, blocked NC/8HW8 layout
__global__ void reduce_relu_pool_kernel(const float* __restrict__ part,
                                        unsigned short* __restrict__ out,
                                        int S, int per, int nChunks, int total)
{
    int idx = blockIdx.x * blockDim.x + threadIdx.x;
    if (idx >= total) return;
    int Sl = 31 - __clz(S);          // log2 S (S pow2)
    int W2 = S >> 1;
    int c8 = idx & 7;
    int t  = idx >> 3;
    int x2 = t & (W2 - 1); t >>= (Sl - 1);
    int y2 = t & (W2 - 1); t >>= (Sl - 1);
    // t = b*(C/8) + cb : plane-row index, used directly
    size_t base = (((size_t)t * S + 2 * y2) * S + 2 * x2) * 8 + c8;
    size_t dX = 8;                    // x+1
    size_t dY = (size_t)S * 8;        // y+1
    float s0 = 0.f, s1 = 0.f, s2 = 0.f, s3 = 0.f;
    for (int ch = 0; ch < nChunks; ++ch) {
        const float* p = part + (size_t)ch * per + base;
        s0 += p[0]; s1 += p[dX]; s2 += p[dY]; s3 += p[dY + dX];
    }
    out[idx] = f2bf(fmaxf(fmaxf(fmaxf(s0, s1), fmaxf(s2, s3)), 0.f));
}

// bf16 2x2 maxpool, blocked NC/8HW8 layout (post-ReLU values; conversions exact)
__global__ void maxpool_kernel(const unsigned short* __restrict__ in,
                               unsigned short* __restrict__ out,
                               int S, int total)
{
    int idx = blockIdx.x * blockDim.x + threadIdx.x;
    if (idx >= total) return;
    int Sl = 31 - __clz(S);
    int W2 = S >> 1;
    int c8 = idx & 7;
    int t  = idx >> 3;
    int x2 = t & (W2 - 1); t >>= (Sl - 1);
    int y2 = t & (W2 - 1); t >>= (Sl - 1);
    size_t base = (((size_t)t * S + 2 * y2) * S + 2 * x2) * 8 + c8;
    size_t dY = (size_t)S * 8;
    const unsigned short* p = in + base;
    float m = fmaxf(fmaxf(bf2f(p[0]), bf2f(p[8])), fmaxf(bf2f(p[dY]), bf2f(p[dY + 8])));
    out[idx] = f2bf(m);
}

// 4x4 avg pool, blocked bf16 (b,64cb,16px,8) in -> fp32 pooled[b][512] out
__global__ void avgpool_kernel(const unsigned short* __restrict__ in,
                               float* __restrict__ out, int total)
{
    int idx = blockIdx.x * blockDim.x + threadIdx.x;
    if (idx >= total) return;
    int b = idx >> 9;
    int c = idx & 511;
    int cb = c >> 3, c8 = c & 7;
    const unsigned short* p = in + (((size_t)(b * 64 + cb) * 16) << 3) + c8;
    float s = 0.f;
#pragma unroll
    for (int i = 0; i < 16; ++i) s += bf2f(p[i * 8]);
    out[idx] = s * (1.0f / 16.0f);
}

__global__ __launch_bounds__(256) void fc_kernel(
    const float* __restrict__ x, const float* __restrict__ w,
    const float* __restrict__ bias, float* __restrict__ out,
    int K, int O, int relu)
{
    int o = blockIdx.x;
    float acc[8] = {0.f,0.f,0.f,0.f,0.f,0.f,0.f,0.f};
    const float* wr = w + (size_t)o * K;
    for (int k = threadIdx.x; k < K; k += 256) {
        float wv = wr[k];
#pragma unroll
        for (int b = 0; b < 8; ++b) acc[b] += wv * x[(size_t)b * K + k];
    }
    __shared__ float red[8][256];
#pragma unroll
    for (int b = 0; b < 8; ++b) red[b][threadIdx.x] = acc[b];
    __syncthreads();
    for (int s = 128; s > 0; s >>= 1) {
        if (threadIdx.x < s) {
#pragma unroll
            for (int b = 0; b < 8; ++b) red[b][threadIdx.x] += red[b][threadIdx.x + s];
        }
        __syncthreads();
    }
    if (threadIdx.x < 8) {
        float v = red[threadIdx.x][0] + bias[o];
        if (relu) v = fmaxf(v, 0.f);
        out[(size_t)threadIdx.x * O + o] = v;
    }
}

// ---------------------------------------------------------------------------
// Host orchestration. Round-7 layout/grids (proven 700 us) + fused prologue
// (5 build_table + 12 pack_w -> 2 launches; the only delta vs round 7).
// ---------------------------------------------------------------------------
extern "C" void kernel_launch(void* const* d_in, const int* in_sizes, int n_in,
                              void* d_out, int out_size, void* d_ws, size_t ws_size,
                              hipStream_t stream) {
    const float* x    = (const float*)d_in[0];
    const float* wf[13];
    for (int i = 0; i < 13; ++i) wf[i] = (const float*)d_in[1 + i];
    const float* fc1w = (const float*)d_in[14];
    const float* fc1b = (const float*)d_in[15];
    const float* fc2w = (const float*)d_in[16];
    const float* fc2b = (const float*)d_in[17];
    const float* fc3w = (const float*)d_in[18];
    const float* fc3b = (const float*)d_in[19];
    float* out = (float*)d_out;

    char* ws = (char*)d_ws;
    auto alloc = [&](size_t bytes) -> char* {
        char* p = ws;
        ws += (bytes + 255) & ~(size_t)255;
        return p;
    };

    const int sizes[5] = {128, 64, 32, 16, 8};
    Tap* tabs[5];
    int* tabAs[5];
    for (int i = 0; i < 5; ++i) {
        int HW = sizes[i] * sizes[i];
        tabs[i]  = (Tap*)alloc((size_t)HW * 9 * sizeof(Tap));
        tabAs[i] = (int*)alloc((size_t)HW * 9 * 8 * sizeof(int));
    }
    unsigned short* actA = (unsigned short*)alloc((size_t)8 * 64 * 128 * 128 * 2);
    unsigned short* actB = (unsigned short*)alloc((size_t)8 * 64 * 128 * 128 * 2);
    float* partial = (float*)alloc((size_t)2 * 8 * 128 * 4096 * sizeof(float)); // 33.55 MB
    const int Cs[13] = {3, 64, 64, 128, 128, 256, 256, 256, 512, 512, 512, 512, 512};
    const int Os[13] = {64, 64, 128, 128, 256, 256, 256, 512, 512, 512, 512, 512, 512};
    unsigned short* wPk[13];
    wPk[0] = nullptr;
    for (int i = 1; i < 13; ++i)
        wPk[i] = (unsigned short*)alloc((size_t)Os[i] * Cs[i] * 9 * sizeof(unsigned short));
    float* pooled = (float*)alloc((size_t)8 * 512 * sizeof(float));
    float* fcb1 = (float*)alloc((size_t)8 * 4096 * sizeof(float));
    float* fcb2 = (float*)alloc((size_t)8 * 4096 * sizeof(float));

    // fused table build (5 sizes, grid.y = size index)
    {
        TabPtrs tp;
        for (int i = 0; i < 5; ++i) { tp.tab[i] = tabs[i]; tp.tabA[i] = tabAs[i]; }
        dim3 grid((128 * 128 * 9 + 255) / 256, 5);
        build_table_all<<<grid, 256, 0, stream>>>(tp);
    }
    // fused weight pack (12 layers)
    {
        PackArgs pa;
        int cum = 0;
        for (int i = 0; i < 12; ++i) {
            pa.w[i]  = wf[i + 1];
            pa.wP[i] = wPk[i + 1];
            pa.O[i]  = Os[i + 1];
            pa.C[i]  = Cs[i + 1];
            cum += Os[i + 1] * Cs[i + 1] * 9;
            pa.tot[i] = cum;
        }
        pack_w_all<<<(cum + 255) / 256, 256, 0, stream>>>(pa, cum);
    }

    auto convM = [&](const unsigned short* in, const unsigned short* wp, int* tabA,
                     unsigned short* o, int C, int O, int S, int nCh, int BM, bool leavePartial) {
        int HW = S * S;
        int Cchunk = C / nCh;
        if (BM == 64) {
            dim3 grid(HW / 64, O / 64, 8 * nCh);
            dconv_mfma<64><<<grid, 256, 0, stream>>>(in, wp, tabA, o, partial, C, O, HW, Cchunk, nCh);
        } else {
            dim3 grid(HW / 64, O / 128, 8 * nCh);
            dconv_mfma<128><<<grid, 256, 0, stream>>>(in, wp, tabA, o, partial, C, O, HW, Cchunk, nCh);
        }
        if (nCh > 1 && !leavePartial) {
            int per4 = 8 * O * HW / 4;
            reduce_relu_kernel<<<(per4 + 255) / 256, 256, 0, stream>>>(partial, o, per4, nCh);
        }
    };
    auto fusedPool = [&](unsigned short* o, int C, int H, int nCh) {
        int per = 8 * C * H * H;
        int total = per / 4;
        reduce_relu_pool_kernel<<<(total + 255) / 256, 256, 0, stream>>>(partial, o, H, per, nCh, total);
    };

    // conv1_1: fp32 input path (C=3) -> bf16 actA (blocked NC/8HW8)
    {
        dim3 grid(128 * 128 / 64, 1, 8);
        dconv_f32_kernel<<<grid, 256, 0, stream>>>(x, wf[0], tabs[0], actA, 3, 64, 128 * 128);
    }
    convM(actA, wPk[1],  tabAs[0], actB, 64,  64,  128, 1, 64, false);   // conv1_2 -> actB
    {
        int total = 8 * 64 * 64 * 64;
        maxpool_kernel<<<(total + 255) / 256, 256, 0, stream>>>(actB, actA, 128, total);
    }
    convM(actA, wPk[2],  tabAs[1], actB, 64,  128, 64, 2, 128, false);   // conv2_1 -> actB
    convM(actB, wPk[3],  tabAs[1], nullptr, 128, 128, 64, 2, 128, true); // conv2_2 -> partial
    fusedPool(actA, 128, 64, 2);                                         // -> actA (128ch @32^2)
    convM(actA, wPk[4],  tabAs[2], actB, 128, 256, 32, 4, 128, false);   // conv3_1 -> actB
    convM(actB, wPk[5],  tabAs[2], actA, 256, 256, 32, 4, 128, false);   // conv3_2 -> actA
    convM(actA, wPk[6],  tabAs[2], nullptr, 256, 256, 32, 4, 128, true); // conv3_3 -> partial
    fusedPool(actB, 256, 32, 4);                                         // -> actB (256ch @16^2)
    convM(actB, wPk[7],  tabAs[3], actA, 256, 512, 16, 8, 128, false);   // conv4_1 -> actA
    convM(actA, wPk[8],  tabAs[3], actB, 512, 512, 16, 8, 128, false);   // conv4_2 -> actB
    convM(actB, wPk[9],  tabAs[3], nullptr, 512, 512, 16, 8, 128, true); // conv4_3 -> partial
    fusedPool(actA, 512, 16, 8);                                         // -> actA (512ch @8^2)
    convM(actA, wPk[10], tabAs[4], actB, 512, 512, 8, 16, 64, false);    // conv5_1 -> actB
    convM(actB, wPk[11], tabAs[4], actA, 512, 512, 8, 16, 64, false);    // conv5_2 -> actA
    convM(actA, wPk[12], tabAs[4], nullptr, 512, 512, 8, 16, 64, true);  // conv5_3 -> partial
    fusedPool(actB, 512, 8, 16);                                         // -> actB (512ch @4^2)

    avgpool_kernel<<<(4096 + 255) / 256, 256, 0, stream>>>(actB, pooled, 8 * 512);

    fc_kernel<<<4096, 256, 0, stream>>>(pooled, fc1w, fc1b, fcb1, 512,  4096, 1);
    fc_kernel<<<4096, 256, 0, stream>>>(fcb1,   fc2w, fc2b, fcb2, 4096, 4096, 1);
    fc_kernel<<<30,   256, 0, stream>>>(fcb2,   fc3w, fc3b, out,  4096, 30,   0);
}